// Round 1
// baseline (114.905 us; speedup 1.0000x reference)
//
#include <hip/hip_runtime.h>
#include <hip/hip_bf16.h>

#define NB 4
#define NC 256
#define NN 4096
#define NCR 32

typedef __attribute__((ext_vector_type(8))) short short8_t;
typedef __attribute__((ext_vector_type(4))) short short4_t;
typedef __attribute__((ext_vector_type(4))) float f32x4;
typedef __attribute__((ext_vector_type(4))) int int4_t;

static __device__ __forceinline__ unsigned short f2bf(float f) {
  unsigned u = __builtin_bit_cast(unsigned, f);
  u += 0x7FFFu + ((u >> 16) & 1u);
  return (unsigned short)(u >> 16);
}

// ---------------------------------------------------------------------------
// Kernel 1: fused QKV projection.
//   D = [Wq; Wk; Wv] (320 x 256) @ x (256 x 4096) per batch, + bias.
//   Outputs: Qt[b][m][r] bf16, Kt[b][n][r] bf16 (transposed, 16B-frag friendly),
//            Vt[b][c][n] bf16.
// Grid: 256 blocks = batch(4) x m-tile(64 of 64 px). 256 threads (4 waves),
// waves split the 320 d-rows (80 each = 5 frags of 16).
// ---------------------------------------------------------------------------
__global__ __launch_bounds__(256) void qkv_kernel(
    const float* __restrict__ x,
    const float* __restrict__ Wq, const float* __restrict__ bq,
    const float* __restrict__ Wk, const float* __restrict__ bk,
    const float* __restrict__ Wv, const float* __restrict__ bv,
    unsigned short* __restrict__ Qt, unsigned short* __restrict__ Kt,
    unsigned short* __restrict__ Vt)
{
  const int bid = blockIdx.x;
  const int b   = bid >> 6;
  const int m0  = (bid & 63) * 64;
  const int tid = threadIdx.x;
  const int w    = tid >> 6;
  const int lane = tid & 63;
  const int lg   = lane >> 4;
  const int lm   = lane & 15;

  const float* xb = x + (size_t)b * NC * NN;

  const f32x4 zero4 = {0.0f, 0.0f, 0.0f, 0.0f};
  f32x4 acc[5][4];
#pragma unroll
  for (int df = 0; df < 5; df++)
#pragma unroll
    for (int mf = 0; mf < 4; mf++) acc[df][mf] = zero4;

  for (int kc = 0; kc < 8; kc++) {
    const int k0 = kc * 32 + lg * 8;
    // B fragments: x[k][m], rows k = k0..k0+7, col m (lane&15)
    short8_t bfr[4];
#pragma unroll
    for (int mf = 0; mf < 4; mf++) {
      const int m = m0 + mf * 16 + lm;
      short8_t t;
#pragma unroll
      for (int i = 0; i < 8; i++) {
        t[i] = (short)f2bf(xb[(size_t)(k0 + i) * NN + m]);
      }
      bfr[mf] = t;
    }
    // A fragments: W rows (contiguous 8 f32 per lane), then MFMA
#pragma unroll
    for (int df = 0; df < 5; df++) {
      const int dbase = w * 80 + df * 16;
      const int d = dbase + lm;
      const float* wrow;
      if (dbase < 32)      wrow = Wq + (size_t)d * NC;
      else if (dbase < 64) wrow = Wk + (size_t)(d - 32) * NC;
      else                 wrow = Wv + (size_t)(d - 64) * NC;
      short8_t a;
#pragma unroll
      for (int i = 0; i < 8; i++) a[i] = (short)f2bf(wrow[k0 + i]);
#pragma unroll
      for (int mf = 0; mf < 4; mf++)
        acc[df][mf] = __builtin_amdgcn_mfma_f32_16x16x32_bf16(a, bfr[mf], acc[df][mf], 0, 0, 0);
    }
  }

  // Epilogue: D frag layout row = 4*lg + i, col = lane&15. Add bias, scatter.
#pragma unroll
  for (int df = 0; df < 5; df++) {
    const int dbase = w * 80 + df * 16;
#pragma unroll
    for (int mf = 0; mf < 4; mf++) {
      const int m = m0 + mf * 16 + lm;
#pragma unroll
      for (int i = 0; i < 4; i++) {
        const int d = dbase + lg * 4 + i;
        float v = acc[df][mf][i];
        if (dbase < 32) {
          v += bq[d];
          Qt[((size_t)b * NN + m) * NCR + d] = f2bf(v);
        } else if (dbase < 64) {
          v += bk[d - 32];
          Kt[((size_t)b * NN + m) * NCR + (d - 32)] = f2bf(v);
        } else {
          v += bv[d - 64];
          Vt[((size_t)(b * NC + (d - 64))) * NN + m] = f2bf(v);
        }
      }
    }
  }
}

// ---------------------------------------------------------------------------
// Kernel 2: fused streaming attention.
//   S = relu(K^T Q) tile (64n x 64m) per iteration; denom[m] accumulated;
//   acc[c][m] += V_tile @ S_tile; epilogue: gamma*acc/denom + x.
// Grid: 256 blocks = batch(4) x m-tile(64). 4 waves:
//   S phase: wave w computes n-rows [16w,16w+16) for all 64 m.
//   PV phase: wave w owns c-rows [64w,64w+64) for all 64 m.
// LDS pitch 72 shorts (144 B): addr/16 mod 8 = (9*row+slot) mod 8 -> distinct
// within every 8 consecutive lanes => conflict-free b128/b64 both sides.
// ---------------------------------------------------------------------------
__global__ __launch_bounds__(256) void attn_kernel(
    const unsigned short* __restrict__ Qt, const unsigned short* __restrict__ Kt,
    const unsigned short* __restrict__ Vt, const float* __restrict__ x,
    const float* __restrict__ gamma, float* __restrict__ out)
{
  __shared__ unsigned short Vlds[NC * 72];   // 36 KB, V tile [256 c][64 n]
  __shared__ unsigned short Slds[64 * 72];   // 9 KB, S^T [64 m][64 n]
  __shared__ float dlds[4][64];

  const int bid = blockIdx.x;
  const int b   = bid >> 6;
  const int m0  = (bid & 63) * 64;
  const int tid = threadIdx.x;
  const int w    = tid >> 6;
  const int lane = tid & 63;
  const int lg   = lane >> 4;
  const int lm   = lane & 15;

  const unsigned short* Qb = Qt + (size_t)b * NN * NCR;
  const unsigned short* Kb = Kt + (size_t)b * NN * NCR;
  const unsigned short* Vb = Vt + (size_t)b * NC * NN;

  // Q fragments (held for the whole kernel): B[r][m], rows r=8*lg..+7
  short8_t qf[4];
#pragma unroll
  for (int mf = 0; mf < 4; mf++) {
    const int m = m0 + mf * 16 + lm;
    qf[mf] = *(const short8_t*)(Qb + (size_t)m * NCR + lg * 8);
  }

  const f32x4 zero4 = {0.0f, 0.0f, 0.0f, 0.0f};
  f32x4 acc[4][4];
#pragma unroll
  for (int cf = 0; cf < 4; cf++)
#pragma unroll
    for (int mf = 0; mf < 4; mf++) acc[cf][mf] = zero4;
  float dsum[4] = {0.f, 0.f, 0.f, 0.f};

  // Prologue: stage tile 0 (V into regs, K frag)
  int4_t vr[8];
#pragma unroll
  for (int j = 0; j < 8; j++) {
    const int slot = j * 256 + tid;
    const int c = slot >> 3, s = slot & 7;
    vr[j] = *(const int4_t*)(Vb + (size_t)c * NN + s * 8);
  }
  short8_t kf = *(const short8_t*)(Kb + (size_t)(w * 16 + lm) * NCR + lg * 8);

  for (int it = 0; it < 64; it++) {
    const int n1 = ((it + 1) & 63) * 64;  // next tile (wraps; last prefetch unused)

    // Prefetch next tile early: latency hides under S+barriers+PV.
    int4_t vrn[8];
#pragma unroll
    for (int j = 0; j < 8; j++) {
      const int slot = j * 256 + tid;
      const int c = slot >> 3, s = slot & 7;
      vrn[j] = *(const int4_t*)(Vb + (size_t)c * NN + n1 + s * 8);
    }
    short8_t kfn = *(const short8_t*)(Kb + (size_t)(n1 + w * 16 + lm) * NCR + lg * 8);

    // S = relu(K^T Q): wave w's 16 n-rows x 64 m. A=K^T frag (contig), B=Q frag.
    f32x4 sfr[4];
#pragma unroll
    for (int mf = 0; mf < 4; mf++)
      sfr[mf] = __builtin_amdgcn_mfma_f32_16x16x32_bf16(kf, qf[mf], zero4, 0, 0, 0);

    short4_t sb[4];
#pragma unroll
    for (int mf = 0; mf < 4; mf++) {
#pragma unroll
      for (int i = 0; i < 4; i++) {
        float v = fmaxf(sfr[mf][i], 0.0f);
        dsum[mf] += v;
        sb[mf][i] = (short)f2bf(v);
      }
    }

    __syncthreads();  // previous iteration's LDS reads complete

    // Write V tile (reg-staged) and S^T to LDS.
#pragma unroll
    for (int j = 0; j < 8; j++) {
      const int slot = j * 256 + tid;
      const int c = slot >> 3, s = slot & 7;
      *(int4_t*)(Vlds + c * 72 + s * 8) = vr[j];
    }
#pragma unroll
    for (int mf = 0; mf < 4; mf++)
      *(short4_t*)(Slds + (mf * 16 + lm) * 72 + w * 16 + lg * 4) = sb[mf];

    __syncthreads();  // LDS ready

    // PV: acc[c][m] += V[c][n] * S[n][m], contraction over this tile's 64 n.
#pragma unroll
    for (int nch = 0; nch < 2; nch++) {
      short8_t sf2[4];
#pragma unroll
      for (int mf = 0; mf < 4; mf++)
        sf2[mf] = *(const short8_t*)(Slds + (mf * 16 + lm) * 72 + nch * 32 + lg * 8);
#pragma unroll
      for (int cf = 0; cf < 4; cf++) {
        const short8_t vf =
            *(const short8_t*)(Vlds + (w * 64 + cf * 16 + lm) * 72 + nch * 32 + lg * 8);
#pragma unroll
        for (int mf = 0; mf < 4; mf++)
          acc[cf][mf] = __builtin_amdgcn_mfma_f32_16x16x32_bf16(vf, sf2[mf], acc[cf][mf], 0, 0, 0);
      }
    }

#pragma unroll
    for (int j = 0; j < 8; j++) vr[j] = vrn[j];
    kf = kfn;
  }

  // Denominator: reduce over the 4 lane-groups holding different n-rows...
#pragma unroll
  for (int mf = 0; mf < 4; mf++) {
    float v = dsum[mf];
    v += __shfl_xor(v, 16);
    v += __shfl_xor(v, 32);
    dsum[mf] = v;
  }
  // ...then across the 4 waves via LDS.
  if (lane < 16) {
#pragma unroll
    for (int mf = 0; mf < 4; mf++) dlds[w][mf * 16 + lane] = dsum[mf];
  }
  __syncthreads();

  const float g0 = gamma[0];
  float rden[4];
#pragma unroll
  for (int mf = 0; mf < 4; mf++) {
    const int mloc = mf * 16 + lm;
    float den = dlds[0][mloc] + dlds[1][mloc] + dlds[2][mloc] + dlds[3][mloc];
    den = den > 1e-12f ? den : 1e-12f;
    rden[mf] = 1.0f / den;
  }

  const float* xb = x + (size_t)b * NC * NN;
  float* ob = out + (size_t)b * NC * NN;
#pragma unroll
  for (int cf = 0; cf < 4; cf++) {
#pragma unroll
    for (int i = 0; i < 4; i++) {
      const int c = w * 64 + cf * 16 + lg * 4 + i;
#pragma unroll
      for (int mf = 0; mf < 4; mf++) {
        const int m = m0 + mf * 16 + lm;
        ob[(size_t)c * NN + m] = g0 * acc[cf][mf][i] * rden[mf] + xb[(size_t)c * NN + m];
      }
    }
  }
}

extern "C" void kernel_launch(void* const* d_in, const int* in_sizes, int n_in,
                              void* d_out, int out_size, void* d_ws, size_t ws_size,
                              hipStream_t stream) {
  const float* x     = (const float*)d_in[0];
  const float* Wq    = (const float*)d_in[1];
  const float* bq    = (const float*)d_in[2];
  const float* Wk    = (const float*)d_in[3];
  const float* bk    = (const float*)d_in[4];
  const float* Wv    = (const float*)d_in[5];
  const float* bv    = (const float*)d_in[6];
  const float* gamma = (const float*)d_in[7];
  float* out = (float*)d_out;

  // Workspace layout (bf16): Qt[4][4096][32], Kt[4][4096][32], Vt[4][256][4096]
  unsigned short* Qt = (unsigned short*)d_ws;
  unsigned short* Kt = Qt + (size_t)NB * NN * NCR;
  unsigned short* Vt = Kt + (size_t)NB * NN * NCR;

  hipLaunchKernelGGL(qkv_kernel, dim3(256), dim3(256), 0, stream,
                     x, Wq, bq, Wk, bk, Wv, bv, Qt, Kt, Vt);
  hipLaunchKernelGGL(attn_kernel, dim3(256), dim3(256), 0, stream,
                     Qt, Kt, Vt, x, gamma, out);
}

// Round 2
// 88.240 us; speedup vs baseline: 1.3022x; 1.3022x over previous
//
#include <hip/hip_runtime.h>
#include <hip/hip_bf16.h>

#define NB 4
#define NC 256
#define NN 4096
#define NCR 32

typedef __attribute__((ext_vector_type(8))) short short8_t;
typedef __attribute__((ext_vector_type(4))) float f32x4;
typedef __attribute__((ext_vector_type(2))) int int2_t;
typedef __attribute__((ext_vector_type(4))) int int4_t;
typedef __attribute__((ext_vector_type(4))) float float4_t;

static __device__ __forceinline__ unsigned short f2bf(float f) {
  unsigned u = __builtin_bit_cast(unsigned, f);
  u += 0x7FFFu + ((u >> 16) & 1u);
  return (unsigned short)(u >> 16);
}

// packed f32x2 -> bf16x2 (RNE), single HW instruction
static __device__ __forceinline__ unsigned cvt_pk(float lo, float hi) {
  unsigned r;
  asm("v_cvt_pk_bf16_f32 %0, %1, %2" : "=v"(r) : "v"(lo), "v"(hi));
  return r;
}

// ---------------------------------------------------------------------------
// Kernel 0: one-time W pack f32 -> bf16, rows: [0,32)=Wq, [32,64)=Wk, [64,320)=Wv
// ---------------------------------------------------------------------------
__global__ __launch_bounds__(64) void pack_w_kernel(
    const float* __restrict__ Wq, const float* __restrict__ Wk,
    const float* __restrict__ Wv, unsigned short* __restrict__ Wbf)
{
  const int row = blockIdx.x;   // 0..319
  const int t = threadIdx.x;    // 0..63
  const float* src = row < 32 ? Wq + (size_t)row * NC
                   : (row < 64 ? Wk + (size_t)(row - 32) * NC
                               : Wv + (size_t)(row - 64) * NC);
  float4_t v = *(const float4_t*)(src + t * 4);
  int2_t p;
  p[0] = cvt_pk(v[0], v[1]);
  p[1] = cvt_pk(v[2], v[3]);
  *(int2_t*)(Wbf + (size_t)row * NC + t * 4) = p;
}

// ---------------------------------------------------------------------------
// Kernel 1: fused QKV projection, D^T = x^T @ W^T per 64-m tile.
// x tile staged in LDS as bf16 [m][k] (XOR-swizzled units), coalesced loads.
// All MFMA swapped: mfma(xfrag, wfrag) -> D^T[m][d] so V stores are b64 along n.
// Grid 256 = batch(4) x m-tile(64), 256 threads (4 waves x 80 d-rows).
// ---------------------------------------------------------------------------
__global__ __launch_bounds__(256) void qkv_kernel(
    const float* __restrict__ x, const unsigned short* __restrict__ Wbf,
    const float* __restrict__ bq, const float* __restrict__ bk,
    const float* __restrict__ bv,
    unsigned short* __restrict__ Qt, unsigned short* __restrict__ Kt,
    unsigned short* __restrict__ Vt)
{
  __shared__ unsigned short xT[2][64 * 32];  // [buf][m][k-swizzled], 4KB each

  const int bid = blockIdx.x;
  const int b   = bid >> 6;
  const int m0  = (bid & 63) * 64;
  const int tid = threadIdx.x;
  const int w    = tid >> 6;
  const int lane = tid & 63;
  const int lg   = lane >> 4;
  const int lm   = lane & 15;

  const float* xb = x + (size_t)b * NC * NN;
  // this thread loads x rows (kc*32 + 8w + j), column m0+lane (coalesced)
  const float* xld = xb + (size_t)(8 * w) * NN + m0 + lane;
  // LDS write slot: row=lane, k-unit = w XOR (row&3)  (conflict-free pairing)
  const int wofs = lane * 32 + ((w ^ (lane & 3)) << 3);
  // W fragment rows: d = w*80 + df*16 + lm
  const unsigned short* wrow = Wbf + (size_t)(w * 80 + lm) * NC;

  const f32x4 zero4 = {0.f, 0.f, 0.f, 0.f};
  f32x4 acc[5][4];
#pragma unroll
  for (int df = 0; df < 5; df++)
#pragma unroll
    for (int mf = 0; mf < 4; mf++) acc[df][mf] = zero4;

  float xg[8], xn[8];
#pragma unroll
  for (int j = 0; j < 8; j++) xg[j] = xld[j * NN];

#define QSTEP(KC, XC, XN, BUF) {                                              \
    if ((KC) < 7) {                                                           \
      _Pragma("unroll") for (int j = 0; j < 8; j++)                           \
        XN[j] = xld[(((KC) + 1) * 32 + j) * NN];                              \
    }                                                                         \
    short8_t wf[5];                                                           \
    _Pragma("unroll") for (int df = 0; df < 5; df++)                          \
      wf[df] = *(const short8_t*)(wrow + df * 16 * NC + (KC) * 32 + lg * 8);  \
    int4_t xw;                                                                \
    xw[0] = cvt_pk(XC[0], XC[1]); xw[1] = cvt_pk(XC[2], XC[3]);               \
    xw[2] = cvt_pk(XC[4], XC[5]); xw[3] = cvt_pk(XC[6], XC[7]);               \
    *(int4_t*)(&xT[BUF][wofs]) = xw;                                          \
    __syncthreads();                                                          \
    short8_t xf[4];                                                           \
    _Pragma("unroll") for (int mf = 0; mf < 4; mf++)                          \
      xf[mf] = *(const short8_t*)(&xT[BUF][(mf * 16 + lm) * 32 +              \
                                          ((lg ^ (lm & 3)) << 3)]);           \
    _Pragma("unroll") for (int df = 0; df < 5; df++)                          \
      _Pragma("unroll") for (int mf = 0; mf < 4; mf++)                        \
        acc[df][mf] = __builtin_amdgcn_mfma_f32_16x16x32_bf16(                \
            xf[mf], wf[df], acc[df][mf], 0, 0, 0);                            \
  }

#pragma unroll
  for (int kc = 0; kc < 8; kc += 2) {
    QSTEP(kc, xg, xn, 0)
    QSTEP(kc + 1, xn, xg, 1)
  }
#undef QSTEP

  // Epilogue. acc[df][mf][i] = D^T[m = m0+mf*16+4lg+i][d = w*80+df*16+lm]
#pragma unroll
  for (int df = 0; df < 5; df++) {
    const int dbase = w * 80 + df * 16;
    if (dbase < 64) {  // q or k rows (wave 0 only) -> scatter b16 into [m][r]
      const bool isq = dbase < 32;
      const float bia = isq ? bq[dbase + lm] : bk[dbase - 32 + lm];
      unsigned short* dst = isq ? Qt : Kt;
      const int dcol = (isq ? dbase : dbase - 32) + lm;
#pragma unroll
      for (int mf = 0; mf < 4; mf++)
#pragma unroll
        for (int i = 0; i < 4; i++) {
          const int m = m0 + mf * 16 + lg * 4 + i;
          dst[((size_t)b * NN + m) * NCR + dcol] = f2bf(acc[df][mf][i] + bia);
        }
    } else {  // V rows -> b64 along n
      const int c = dbase - 64 + lm;
      const float bia = bv[c];
#pragma unroll
      for (int mf = 0; mf < 4; mf++) {
        int2_t p;
        p[0] = cvt_pk(acc[df][mf][0] + bia, acc[df][mf][1] + bia);
        p[1] = cvt_pk(acc[df][mf][2] + bia, acc[df][mf][3] + bia);
        *(int2_t*)(Vt + ((size_t)b * NC + c) * NN + m0 + mf * 16 + lg * 4) = p;
      }
    }
  }
}

// ---------------------------------------------------------------------------
// Kernel 2: streaming attention. V fragments straight from global (Vt[c][n] is
// fragment-layout-compatible); only S crosses waves via double-buffered LDS
// (1 barrier/iter). Grid 256 = batch x m-tile, XCD-swizzled; 4 waves.
// ---------------------------------------------------------------------------
__global__ __launch_bounds__(256) void attn_kernel(
    const unsigned short* __restrict__ Qt, const unsigned short* __restrict__ Kt,
    const unsigned short* __restrict__ Vt, const float* __restrict__ x,
    const float* __restrict__ gamma, float* __restrict__ out)
{
  __shared__ unsigned short Slds[2][64 * 72];  // S^T [m][n], pitch 72
  __shared__ float dlds[4][64];

  int bid = blockIdx.x;
  bid = (bid & 7) * 32 + (bid >> 3);  // bijective XCD swizzle: XCD pair per batch
  const int b   = bid >> 6;
  const int m0  = (bid & 63) * 64;
  const int tid = threadIdx.x;
  const int w    = tid >> 6;
  const int lane = tid & 63;
  const int lg   = lane >> 4;
  const int lm   = lane & 15;

  const unsigned short* Qb = Qt + (size_t)b * NN * NCR;
  const unsigned short* Kb = Kt + (size_t)b * NN * NCR + (w * 16 + lm) * NCR + lg * 8;
  const unsigned short* Vb = Vt + (size_t)b * NC * NN;
  const unsigned short* pV[4];
#pragma unroll
  for (int cf = 0; cf < 4; cf++)
    pV[cf] = Vb + (size_t)(w * 64 + cf * 16 + lm) * NN + lg * 8;

  short8_t qf[4];
#pragma unroll
  for (int mf = 0; mf < 4; mf++)
    qf[mf] = *(const short8_t*)(Qb + (size_t)(m0 + mf * 16 + lm) * NCR + lg * 8);

  const f32x4 zero4 = {0.f, 0.f, 0.f, 0.f};
  f32x4 acc[4][4];
#pragma unroll
  for (int cf = 0; cf < 4; cf++)
#pragma unroll
    for (int mf = 0; mf < 4; mf++) acc[cf][mf] = zero4;
  float dsum[4] = {0.f, 0.f, 0.f, 0.f};

  // prologue: tile 0 K + V fragments
  short8_t kA, kB, vA[4][2], vB[4][2];
  kA = *(const short8_t*)(Kb);
#pragma unroll
  for (int cf = 0; cf < 4; cf++)
#pragma unroll
    for (int nch = 0; nch < 2; nch++)
      vA[cf][nch] = *(const short8_t*)(pV[cf] + nch * 32);

  const int swofs = w * 16 + lg * 4;

#define AITER(T, VC, VN, KC, KN, BUF) {                                       \
    const int n1 = (((T) + 1) & 63) * 64;                                     \
    KN = *(const short8_t*)(Kb + (size_t)n1 * NCR);                           \
    _Pragma("unroll") for (int cf = 0; cf < 4; cf++)                          \
      _Pragma("unroll") for (int nch = 0; nch < 2; nch++)                     \
        VN[cf][nch] = *(const short8_t*)(pV[cf] + n1 + nch * 32);             \
    _Pragma("unroll") for (int mf = 0; mf < 4; mf++) {                        \
      f32x4 s = __builtin_amdgcn_mfma_f32_16x16x32_bf16(KC, qf[mf], zero4, 0, 0, 0); \
      float s0 = fmaxf(s[0], 0.f), s1 = fmaxf(s[1], 0.f);                     \
      float s2 = fmaxf(s[2], 0.f), s3 = fmaxf(s[3], 0.f);                     \
      dsum[mf] += (s0 + s1) + (s2 + s3);                                      \
      int2_t p; p[0] = cvt_pk(s0, s1); p[1] = cvt_pk(s2, s3);                 \
      *(int2_t*)(&Slds[BUF][(mf * 16 + lm) * 72 + swofs]) = p;                \
    }                                                                         \
    __syncthreads();                                                          \
    _Pragma("unroll") for (int nch = 0; nch < 2; nch++) {                     \
      short8_t sf[4];                                                         \
      _Pragma("unroll") for (int mf = 0; mf < 4; mf++)                        \
        sf[mf] = *(const short8_t*)(&Slds[BUF][(mf * 16 + lm) * 72 + nch * 32 + lg * 8]); \
      _Pragma("unroll") for (int cf = 0; cf < 4; cf++)                        \
        _Pragma("unroll") for (int mf = 0; mf < 4; mf++)                      \
          acc[cf][mf] = __builtin_amdgcn_mfma_f32_16x16x32_bf16(              \
              VC[cf][nch], sf[mf], acc[cf][mf], 0, 0, 0);                     \
    }                                                                         \
  }

#pragma unroll 1
  for (int t = 0; t < 64; t += 2) {
    AITER(t, vA, vB, kA, kB, 0)
    AITER(t + 1, vB, vA, kB, kA, 1)
  }
#undef AITER

  // denominator reduce: lg-groups via shuffle, waves via LDS
#pragma unroll
  for (int mf = 0; mf < 4; mf++) {
    float v = dsum[mf];
    v += __shfl_xor(v, 16);
    v += __shfl_xor(v, 32);
    dsum[mf] = v;
  }
  if (lane < 16) {
#pragma unroll
    for (int mf = 0; mf < 4; mf++) dlds[w][mf * 16 + lane] = dsum[mf];
  }
  __syncthreads();

  const float g0 = gamma[0];
  float rden[4];
#pragma unroll
  for (int mf = 0; mf < 4; mf++) {
    const int mloc = mf * 16 + lm;
    float den = dlds[0][mloc] + dlds[1][mloc] + dlds[2][mloc] + dlds[3][mloc];
    den = den > 1e-12f ? den : 1e-12f;
    rden[mf] = 1.0f / den;
  }

  const float* xb = x + (size_t)b * NC * NN;
  float* ob = out + (size_t)b * NC * NN;
#pragma unroll
  for (int cf = 0; cf < 4; cf++) {
#pragma unroll
    for (int i = 0; i < 4; i++) {
      const int c = w * 64 + cf * 16 + lg * 4 + i;
#pragma unroll
      for (int mf = 0; mf < 4; mf++) {
        const int m = m0 + mf * 16 + lm;
        ob[(size_t)c * NN + m] = g0 * acc[cf][mf][i] * rden[mf] + xb[(size_t)c * NN + m];
      }
    }
  }
}

extern "C" void kernel_launch(void* const* d_in, const int* in_sizes, int n_in,
                              void* d_out, int out_size, void* d_ws, size_t ws_size,
                              hipStream_t stream) {
  const float* x     = (const float*)d_in[0];
  const float* Wq    = (const float*)d_in[1];
  const float* bq    = (const float*)d_in[2];
  const float* Wk    = (const float*)d_in[3];
  const float* bk    = (const float*)d_in[4];
  const float* Wv    = (const float*)d_in[5];
  const float* bv    = (const float*)d_in[6];
  const float* gamma = (const float*)d_in[7];
  float* out = (float*)d_out;

  // ws layout (bf16): Wbf[320][256], Qt[4][4096][32], Kt[4][4096][32], Vt[4][256][4096]
  unsigned short* Wbf = (unsigned short*)d_ws;
  unsigned short* Qt  = Wbf + (size_t)320 * NC;
  unsigned short* Kt  = Qt + (size_t)NB * NN * NCR;
  unsigned short* Vt  = Kt + (size_t)NB * NN * NCR;

  hipLaunchKernelGGL(pack_w_kernel, dim3(320), dim3(64), 0, stream,
                     Wq, Wk, Wv, Wbf);
  hipLaunchKernelGGL(qkv_kernel, dim3(256), dim3(256), 0, stream,
                     x, Wbf, bq, bk, bv, Qt, Kt, Vt);
  hipLaunchKernelGGL(attn_kernel, dim3(256), dim3(256), 0, stream,
                     Qt, Kt, Vt, x, gamma, out);
}